// Round 2
// 399.032 us; speedup vs baseline: 1.0080x; 1.0080x over previous
//
#include <hip/hip_runtime.h>
#include <cstdint>
#include <cstddef>

#define NTOT 6144
#define NDRUG 3072
#define NM (NTOT*64)

typedef __fp16 f16;
typedef __attribute__((ext_vector_type(4))) __fp16 f16x4;
typedef __attribute__((ext_vector_type(8))) __fp16 f16x8;
typedef __attribute__((ext_vector_type(4))) float f32x4;

// ------- Kernel 1: rowsum -> norm; write fp16 graph copy; nfs^T in fp16 -----
// Per wave: one row. Reads fp32 graph (151 MB), writes fp16 copy (75 MB),
// computes norm + per-type projection, emits nfst[64][6144] fp16 (B-operand
// layout for k_gemm: transposed, so k_gemm staging is a pure vector copy).
__global__ __launch_bounds__(256) void k_deg(const float* __restrict__ g,
                                             const float* __restrict__ drug_f,
                                             const float* __restrict__ dis_f,
                                             const float* __restrict__ drug_w,
                                             const float* __restrict__ dis_w,
                                             float* __restrict__ norm,
                                             f16* __restrict__ gh,
                                             f16* __restrict__ nfst){
  __shared__ float sx[4][64];
  __shared__ float snf[4][64];
  int wv = threadIdx.x >> 6, j = threadIdx.x & 63;
  int row = blockIdx.x*4 + wv;
  const float4* p = (const float4*)(g + (size_t)row * NTOT);
  f16* ghrow = gh + (size_t)row * NTOT;
  float s = 0.f;
  #pragma unroll
  for (int it = 0; it < 24; ++it) {
    float4 u = p[it*64 + j];
    s += (u.x + u.y) + (u.z + u.w);
    f16x4 pk = {(f16)u.x, (f16)u.y, (f16)u.z, (f16)u.w};
    *(f16x4*)(ghrow + (size_t)(it*64 + j)*4) = pk;
  }
  #pragma unroll
  for (int off = 32; off; off >>= 1) s += __shfl_xor(s, off, 64);
  float nrm = rsqrtf(fmaxf(s, 1.0f));
  if (j == 0) norm[row] = nrm;

  const float* x; const float* W;
  if (row < NDRUG){ x = drug_f + (size_t)row*64; W = drug_w; }
  else            { x = dis_f + (size_t)(row-NDRUG)*64; W = dis_w; }
  sx[wv][j] = x[j];
  __syncthreads();
  float acc = 0.f;
  #pragma unroll 8
  for (int k = 0; k < 64; ++k) acc = fmaf(sx[wv][k], W[k*64+j], acc);
  snf[wv][j] = acc * nrm;
  __syncthreads();
  if (threadIdx.x < 64){
    int c = threadIdx.x;
    f16x4 pk = {(f16)snf[0][c], (f16)snf[1][c], (f16)snf[2][c], (f16)snf[3][c]};
    *(f16x4*)(nfst + (size_t)c*NTOT + blockIdx.x*4) = pk;
  }
}

// ---------------- Kernel 2: MFMA split-K GEMM: part[ks] = graph_tile @ nfs ---
// grid (96, 8), block 256 = 4 waves. 64x64 tile, K-range 768 per slice.
// Both operands pre-converted fp16 (gh row-major, nfst transposed) -> staging
// is a pure 16B-vector copy. Register-staged double buffer, ONE barrier/kt:
// loads for kt+1 issued before the barrier, ds_writes after compute.
__global__ __launch_bounds__(256) void k_gemm(const f16* __restrict__ gh,
                                              const f16* __restrict__ nfst,
                                              float* __restrict__ part){
  __shared__ f16 sA[2][64][72];
  __shared__ f16 sB[2][64][72];
  const int tid = threadIdx.x;
  const int lane = tid & 63, w = tid >> 6;
  const int l15 = lane & 15, quad = lane >> 4;
  const int row0 = blockIdx.x * 64;
  const int kbase = blockIdx.y * 768;
  const int sr = tid >> 2, scg = (tid & 3) * 16;

  f32x4 acc[4] = {{0.f,0.f,0.f,0.f},{0.f,0.f,0.f,0.f},
                  {0.f,0.f,0.f,0.f},{0.f,0.f,0.f,0.f}};
  f16x8 ra0, ra1, rb0, rb1;
  auto LOADT = [&](int kt){
    const f16* pa = gh + (size_t)(row0 + sr)*NTOT + kbase + kt*64 + scg;
    ra0 = *(const f16x8*)pa; ra1 = *(const f16x8*)(pa + 8);
    const f16* pb = nfst + (size_t)sr*NTOT + kbase + kt*64 + scg;
    rb0 = *(const f16x8*)pb; rb1 = *(const f16x8*)(pb + 8);
  };
  auto WRITET = [&](int b){
    *(f16x8*)&sA[b][sr][scg]     = ra0;
    *(f16x8*)&sA[b][sr][scg + 8] = ra1;
    *(f16x8*)&sB[b][sr][scg]     = rb0;
    *(f16x8*)&sB[b][sr][scg + 8] = rb1;
  };
  LOADT(0); WRITET(0);
  int cur = 0;
  for (int kt = 0; kt < 12; ++kt){
    if (kt < 11) LOADT(kt + 1);
    __syncthreads();
    #pragma unroll
    for (int k16 = 0; k16 < 4; ++k16){
      f16x4 af = *(const f16x4*)&sA[cur][w*16 + l15][k16*16 + quad*4];
      #pragma unroll
      for (int nt = 0; nt < 4; ++nt){
        f16x4 bf = *(const f16x4*)&sB[cur][nt*16 + l15][k16*16 + quad*4];
        acc[nt] = __builtin_amdgcn_mfma_f32_16x16x16f16(af, bf, acc[nt], 0, 0, 0);
      }
    }
    if (kt < 11) WRITET(cur ^ 1);
    cur ^= 1;
  }
  float* dst = part + (size_t)blockIdx.y * NM;
  #pragma unroll
  for (int nt = 0; nt < 4; ++nt){
    #pragma unroll
    for (int r = 0; r < 4; ++r){
      int row = row0 + w*16 + quad*4 + r;
      dst[(size_t)row*64 + nt*16 + l15] = acc[nt][r];
    }
  }
}

// ------- Kernel 3: finish + time-emb MLP + qkv (fused) -----------------------
// Emits q (pre-scaled by 0.25, fp16), k (fp16 row-major), v (fp16
// TRANSPOSED [d][key]) so k_attn staging is a pure vector copy.
__global__ __launch_bounds__(256) void k_node2(const float* __restrict__ part,
                                               const float* __restrict__ norm,
                                               const int* __restrict__ ts,
                                               const float* __restrict__ emb_w,
                                               const float* __restrict__ emb_b,
                                               const float* __restrict__ in_w,
                                               const float* __restrict__ in_b,
                                               const float* __restrict__ out_w,
                                               const float* __restrict__ out_b,
                                               const float* __restrict__ wq, const float* __restrict__ bq,
                                               const float* __restrict__ wk, const float* __restrict__ bk,
                                               const float* __restrict__ wvw, const float* __restrict__ bv,
                                               float* __restrict__ target,
                                               f16* __restrict__ qh, f16* __restrict__ kh,
                                               f16* __restrict__ vt){
  __shared__ float sx[4][80];    // [0..63]=target row, [64..79]=time emb
  __shared__ float sh[4][256];
  __shared__ float sa[4][64];    // aux row (LDS only)
  __shared__ float sv[4][64];    // v row (for transpose)
  int wv = threadIdx.x>>6, j = threadIdx.x&63;
  int row = blockIdx.x*4 + wv;

  float t = 0.f;
  #pragma unroll
  for (int p = 0; p < 8; ++p) t += part[(size_t)p*NM + (size_t)row*64 + j];
  t *= norm[row];
  target[(size_t)row*64 + j] = t;
  sx[wv][j] = t;
  if (j < 16) {
    const float FREQ[8] = {1.0f, 0.316227766016838f, 0.1f, 0.0316227766016838f,
                           0.01f, 0.00316227766016838f, 0.001f, 0.000316227766016838f};
    float tt = (float)ts[row];
    float e = emb_b[j];
    #pragma unroll
    for (int k = 0; k < 8; ++k) {
      float a = tt * FREQ[k];
      e = fmaf(cosf(a), emb_w[k*16 + j], e);
      e = fmaf(sinf(a), emb_w[(8+k)*16 + j], e);
    }
    sx[wv][64 + j] = e;
  }
  __syncthreads();
  float a0 = in_b[4*j+0], a1 = in_b[4*j+1], a2 = in_b[4*j+2], a3 = in_b[4*j+3];
  #pragma unroll 8
  for (int k = 0; k < 80; ++k) {
    float xv = sx[wv][k];
    float4 w = *(const float4*)(in_w + k*256 + 4*j);
    a0 = fmaf(xv, w.x, a0);
    a1 = fmaf(xv, w.y, a1);
    a2 = fmaf(xv, w.z, a2);
    a3 = fmaf(xv, w.w, a3);
  }
  sh[wv][4*j+0] = tanhf(a0); sh[wv][4*j+1] = tanhf(a1);
  sh[wv][4*j+2] = tanhf(a2); sh[wv][4*j+3] = tanhf(a3);
  __syncthreads();
  float o = out_b[j];
  #pragma unroll 8
  for (int k = 0; k < 256; ++k) o = fmaf(sh[wv][k], out_w[k*64 + j], o);
  sa[wv][j] = o;
  __syncthreads();
  float q = bq[j], kk = bk[j], vv = bv[j];
  #pragma unroll 8
  for (int k = 0; k < 64; ++k) {
    float tv = sx[wv][k], av = sa[wv][k];
    q  = fmaf(tv, wq[k*64+j],  q);
    kk = fmaf(av, wk[k*64+j],  kk);
    vv = fmaf(av, wvw[k*64+j], vv);
  }
  // q pre-scaled by 1/sqrt(hd)=0.25 (exact power-of-2, commutes with fp16 rounding)
  qh[(size_t)row*64+j] = (f16)(q * 0.25f);
  kh[(size_t)row*64+j] = (f16)kk;
  sv[wv][j] = vv;
  __syncthreads();
  if (threadIdx.x < 64){
    int c = threadIdx.x;
    f16x4 pk = {(f16)sv[0][c], (f16)sv[1][c], (f16)sv[2][c], (f16)sv[3][c]};
    *(f16x4*)(vt + (size_t)c*NTOT + blockIdx.x*4) = pk;
  }
}

// ---------------- Kernel 4: MFMA flash attention per-slice partials ----------
// grid (96 qblocks, 8 z-slices), block 256 = 4 waves; wave = head.
// S^T = mfma(A=K, B=Q); P^T feeds O^T = mfma(A=V^T, B=P^T) in-register.
// K/V pre-converted fp16 (V pre-transposed) -> staging is pure vector copy;
// register-staged double buffer, one barrier per kt.
// Record per (slice,head,row), stride 20: [0..15]=O^T (unnormalized), [17]=l.
__global__ __launch_bounds__(256) void k_attn(const f16* __restrict__ qh,
                                              const f16* __restrict__ kh,
                                              const f16* __restrict__ vt,
                                              float* __restrict__ pattn){
  __shared__ f16 sK[2][64][72];   // [key][d]
  __shared__ f16 sV[2][64][72];   // [d][key]
  const int tid = threadIdx.x;
  const int h = tid >> 6;
  const int lane = tid & 63;
  const int l15 = lane & 15, quad = lane >> 4;
  const int z = blockIdx.y;
  const int q0 = blockIdx.x * 64;

  f16x4 qf[4];
  #pragma unroll
  for (int qn = 0; qn < 4; ++qn)
    qf[qn] = *(const f16x4*)(qh + (size_t)(q0 + qn*16 + l15)*64 + h*16 + quad*4);

  f32x4 accOT[4] = {{0.f,0.f,0.f,0.f},{0.f,0.f,0.f,0.f},
                    {0.f,0.f,0.f,0.f},{0.f,0.f,0.f,0.f}};
  float lsum[4] = {0.f, 0.f, 0.f, 0.f};
  const int sr = tid >> 2, scg = (tid & 3) * 16;
  const int kbase = z * 768;
  f16x8 rk0, rk1, rv0, rv1;
  auto LOADT = [&](int kt){
    const int k0 = kbase + kt*64;
    const f16* pk = kh + (size_t)(k0 + sr)*64 + scg;
    rk0 = *(const f16x8*)pk; rk1 = *(const f16x8*)(pk + 8);
    const f16* pv = vt + (size_t)sr*NTOT + k0 + scg;
    rv0 = *(const f16x8*)pv; rv1 = *(const f16x8*)(pv + 8);
  };
  auto WRITET = [&](int b){
    *(f16x8*)&sK[b][sr][scg]     = rk0;
    *(f16x8*)&sK[b][sr][scg + 8] = rk1;
    *(f16x8*)&sV[b][sr][scg]     = rv0;
    *(f16x8*)&sV[b][sr][scg + 8] = rv1;
  };
  LOADT(0); WRITET(0);
  int cur = 0;
  for (int kt = 0; kt < 12; ++kt){
    if (kt < 11) LOADT(kt + 1);
    __syncthreads();
    #pragma unroll
    for (int km = 0; km < 4; ++km){
      f16x4 kf = *(const f16x4*)&sK[cur][km*16 + l15][h*16 + quad*4];
      f16x4 vf = *(const f16x4*)&sV[cur][h*16 + l15][km*16 + quad*4];
      #pragma unroll
      for (int qn = 0; qn < 4; ++qn){
        f32x4 s = __builtin_amdgcn_mfma_f32_16x16x16f16(
            kf, qf[qn], (f32x4){0.f,0.f,0.f,0.f}, 0, 0, 0);
        float p0 = __expf(fminf(s[0], 10.f));
        float p1 = __expf(fminf(s[1], 10.f));
        float p2 = __expf(fminf(s[2], 10.f));
        float p3 = __expf(fminf(s[3], 10.f));
        lsum[qn] += (p0 + p1) + (p2 + p3);
        f16x4 pf;
        pf[0] = (f16)p0; pf[1] = (f16)p1; pf[2] = (f16)p2; pf[3] = (f16)p3;
        accOT[qn] = __builtin_amdgcn_mfma_f32_16x16x16f16(vf, pf, accOT[qn], 0, 0, 0);
      }
    }
    if (kt < 11) WRITET(cur ^ 1);
    cur ^= 1;
  }
  #pragma unroll
  for (int qn = 0; qn < 4; ++qn){
    lsum[qn] += __shfl_xor(lsum[qn], 16, 64);
    lsum[qn] += __shfl_xor(lsum[qn], 32, 64);
  }
  #pragma unroll
  for (int qn = 0; qn < 4; ++qn){
    float* rec = pattn + ((size_t)(z*4 + h)*NTOT + q0 + qn*16 + l15) * 20;
    *(float4*)(rec + quad*4) =
        make_float4(accOT[qn][0], accOT[qn][1], accOT[qn][2], accOT[qn][3]);
    if (quad == 0){ rec[17] = lsum[qn]; }
  }
}

// ------- Kernel 5: combine slices + out-proj + fuse + residual LN (fused) ----
__global__ __launch_bounds__(256) void k_out(const float* __restrict__ pattn,
                                             const float* __restrict__ target,
                                             const float* __restrict__ wo, const float* __restrict__ bo,
                                             const float* __restrict__ fuse_w, const float* __restrict__ fuse_b,
                                             const float* __restrict__ ln_g, const float* __restrict__ ln_b,
                                             float* __restrict__ out){
  __shared__ float st[4][64], sa[4][64], sao[4][64];
  int wv = threadIdx.x>>6, j = threadIdx.x&63;
  int row = blockIdx.x*4 + wv;
  int h = j >> 4, d = j & 15;
  float osum = 0.f, L = 0.f;
  #pragma unroll
  for (int z = 0; z < 8; ++z) {
    const float* rec = pattn + ((size_t)(z*4 + h)*NTOT + row)*20;
    osum += rec[d];
    L += rec[17];
  }
  sa[wv][j] = osum / L;
  st[wv][j] = target[(size_t)row*64+j];
  __syncthreads();
  float ao = bo[j];
  #pragma unroll 8
  for (int k = 0; k < 64; ++k) ao = fmaf(sa[wv][k], wo[k*64+j], ao);
  sao[wv][j] = ao;
  __syncthreads();
  float f = fuse_b[j];
  #pragma unroll 8
  for (int k = 0; k < 64; ++k) f = fmaf(st[wv][k], fuse_w[k*64+j], f);
  #pragma unroll 8
  for (int k = 0; k < 64; ++k) f = fmaf(sao[wv][k], fuse_w[(64+k)*64+j], f);
  float x = f + st[wv][j];
  float s1 = x, s2 = x*x;
  #pragma unroll
  for (int off = 32; off; off >>= 1) { s1 += __shfl_xor(s1, off, 64); s2 += __shfl_xor(s2, off, 64); }
  float mu = s1*(1.f/64.f);
  float var = s2*(1.f/64.f) - mu*mu;
  float y = (x-mu)*rsqrtf(var + 1e-5f)*ln_g[j] + ln_b[j];
  out[(size_t)row*64 + j] = y;
}

extern "C" void kernel_launch(void* const* d_in, const int* in_sizes, int n_in,
                              void* d_out, int out_size, void* d_ws, size_t ws_size,
                              hipStream_t stream) {
  const float* graph  = (const float*)d_in[0];
  const float* drug_f = (const float*)d_in[1];
  const float* dis_f  = (const float*)d_in[2];
  const int*   ts     = (const int*)d_in[3];
  const float* drug_w = (const float*)d_in[4];
  const float* dis_w  = (const float*)d_in[5];
  const float* emb_w  = (const float*)d_in[6];
  const float* emb_b  = (const float*)d_in[7];
  const float* in_w   = (const float*)d_in[8];
  const float* in_b   = (const float*)d_in[9];
  const float* out_w  = (const float*)d_in[10];
  const float* out_b  = (const float*)d_in[11];
  const float* wq     = (const float*)d_in[12];
  const float* bq     = (const float*)d_in[13];
  const float* wk     = (const float*)d_in[14];
  const float* bk     = (const float*)d_in[15];
  const float* wvw    = (const float*)d_in[16];
  const float* bv     = (const float*)d_in[17];
  const float* wo     = (const float*)d_in[18];
  const float* bo     = (const float*)d_in[19];
  const float* fuse_w = (const float*)d_in[20];
  const float* fuse_b = (const float*)d_in[21];
  const float* ln_g   = (const float*)d_in[22];
  const float* ln_b   = (const float*)d_in[23];

  float* ws     = (float*)d_ws;
  float* norm   = ws;                                     // 8192 (6144 used)
  f16*   gh     = (f16*)(ws + 8192);                      // NTOT*NTOT halves
  float* base   = ws + 8192 + (size_t)NTOT*NTOT/2;
  f16*   nfst   = (f16*)base;                             // 64*NTOT halves
  float* target = base + (size_t)64*NTOT/2;               // NM floats
  f16*   qh     = (f16*)(target + NM);                    // NM halves
  f16*   kh     = (f16*)(target + NM + NM/2);             // NM halves
  f16*   vt     = (f16*)(target + NM + NM);               // NM halves
  float* part   = target + NM + NM + NM/2;                // 8*NM floats
  float* pattn  = part + (size_t)8*NM;                    // 8*4*6144*20 floats

  k_deg<<<1536, 256, 0, stream>>>(graph, drug_f, dis_f, drug_w, dis_w, norm, gh, nfst);
  k_gemm<<<dim3(96, 8), 256, 0, stream>>>(gh, nfst, part);
  k_node2<<<1536, 256, 0, stream>>>(part, norm, ts, emb_w, emb_b, in_w, in_b,
                                    out_w, out_b, wq, bq, wk, bk, wvw, bv,
                                    target, qh, kh, vt);
  k_attn<<<dim3(96, 8), 256, 0, stream>>>(qh, kh, vt, pattn);
  k_out<<<1536, 256, 0, stream>>>(pattn, target, wo, bo, fuse_w, fuse_b,
                                  ln_g, ln_b, (float*)d_out);
}